// Round 1
// baseline (369.886 us; speedup 1.0000x reference)
//
#include <hip/hip_runtime.h>
#include <math.h>

// PGTAttention fused block, MI355X gfx950.
// Pipeline: cast/transpose prep -> bf16 MFMA GEMM (qkv) -> V transpose ->
//           flash attention (+fused PMSNorm) -> bf16 MFMA GEMM (proj, fp32 out).
// All MFMA fragment layouts per HW-verified gfx950 mappings:
//   A/B operand (16x16x32 bf16): lane holds row (lane&15), k = (lane>>4)*8 + j (contiguous 8)
//   C/D: col = lane&15, row = (lane>>4)*4 + reg

typedef unsigned short u16;
typedef unsigned int   u32;
typedef u16   u16x8 __attribute__((ext_vector_type(8)));
typedef __bf16 bf16x8 __attribute__((ext_vector_type(8)));
typedef float f32x4 __attribute__((ext_vector_type(4)));

#define GPTR(p) ((const __attribute__((address_space(1))) void*)(p))
#define LPTR(p) ((__attribute__((address_space(3))) void*)(p))

__device__ __forceinline__ u16 f2bf(float x) {
  u32 u = __float_as_uint(x);
  return (u16)((u + 0x7fffu + ((u >> 16) & 1u)) >> 16);  // RNE
}

__device__ __forceinline__ bf16x8 ld8(const void* p) {
  u16x8 v = *reinterpret_cast<const u16x8*>(p);
  return __builtin_bit_cast(bf16x8, v);
}

// global->LDS direct copy, 16B per lane. LDS dest is wave-uniform base + lane*16.
__device__ __forceinline__ void g2l16(const void* g, void* l) {
#if __has_builtin(__builtin_amdgcn_global_load_lds)
  __builtin_amdgcn_global_load_lds(GPTR(g), LPTR(l), 16, 0, 0);
#else
  int lane = threadIdx.x & 63;
  u16x8 v = *reinterpret_cast<const u16x8*>(g);
  *reinterpret_cast<u16x8*>((char*)l + lane * 16) = v;
#endif
}

// ---------------- elementwise cast f32 -> bf16, 8 elems/thread ----------------
__global__ void cast_bf16_kernel(const float* __restrict__ in, u16* __restrict__ out, int n8) {
  int i = blockIdx.x * 256 + threadIdx.x;
  if (i >= n8) return;
  const float4* p = reinterpret_cast<const float4*>(in) + (size_t)i * 2;
  float4 a = p[0], b = p[1];
  u16x8 v;
  v[0] = f2bf(a.x); v[1] = f2bf(a.y); v[2] = f2bf(a.z); v[3] = f2bf(a.w);
  v[4] = f2bf(b.x); v[5] = f2bf(b.y); v[6] = f2bf(b.z); v[7] = f2bf(b.w);
  reinterpret_cast<u16x8*>(out)[i] = v;
}

// ---------------- transpose + cast: out[c][r] = bf16(in[r][c]), in is R x C f32 ---------
__global__ void tcast_kernel(const float* __restrict__ in, u16* __restrict__ out, int R, int C) {
  __shared__ float t[32][33];
  int bx = blockIdx.x * 32, by = blockIdx.y * 32;
  int x = threadIdx.x, y = threadIdx.y;  // (32, 8)
  #pragma unroll
  for (int k = 0; k < 32; k += 8)
    t[y + k][x] = in[(size_t)(by + y + k) * C + (bx + x)];
  __syncthreads();
  #pragma unroll
  for (int k = 0; k < 32; k += 8)
    out[(size_t)(bx + y + k) * R + (by + x)] = f2bf(t[x][y + k]);
}

// ---------------- batched bf16 transpose: out[bh][d][s] = in[bh][s][d] (S=2048,D=256) ----
__global__ void tv_kernel(const u16* __restrict__ in, u16* __restrict__ out) {
  __shared__ u16 t[32][33];
  int bh = blockIdx.z;
  const u16* ip = in + (size_t)bh * 2048 * 256;
  u16* op = out + (size_t)bh * 2048 * 256;
  int bx = blockIdx.x * 32, by = blockIdx.y * 32;  // bx: d, by: s
  int x = threadIdx.x, y = threadIdx.y;
  #pragma unroll
  for (int k = 0; k < 32; k += 8)
    t[y + k][x] = ip[(size_t)(by + y + k) * 256 + (bx + x)];
  __syncthreads();
  #pragma unroll
  for (int k = 0; k < 32; k += 8)
    op[(size_t)(bx + y + k) * 2048 + (by + x)] = t[x][y + k];
}

// ---------------- m97-structure GEMM: C[M,N] = A[M,K] * Bt[N,K]^T  (bf16 in, f32 acc) ----
// 128x128 tile, BK=32, 4 waves (each 64x64). mode 0: fp32 C. mode 1: split-QKV bf16 epilogue.
// LDS rows are 64B; XOR swizzle bits 4-5 by (row&3) applied on BOTH stage-source and read.
__global__ __launch_bounds__(256) void gemm_bt_kernel(
    const u16* __restrict__ A, const u16* __restrict__ Bt,
    float* __restrict__ Cf, u16* __restrict__ Qb, u16* __restrict__ Kb, u16* __restrict__ Vb,
    int M, int N, int K, int mode) {
  __shared__ __align__(16) u16 sA[128 * 32];  // 8 KiB
  __shared__ __align__(16) u16 sB[128 * 32];  // 8 KiB
  const int tid = threadIdx.x;
  const int lane = tid & 63, w = tid >> 6;
  const int wr = w >> 1, wc = w & 1;
  const int g = lane >> 4, li = lane & 15;
  const int bn = blockIdx.x * 128, bm = blockIdx.y * 128;

  const f32x4 fz = {0.f, 0.f, 0.f, 0.f};
  f32x4 acc[4][4];
  #pragma unroll
  for (int i = 0; i < 4; ++i)
    #pragma unroll
    for (int j = 0; j < 4; ++j) acc[i][j] = fz;

  for (int k0 = 0; k0 < K; k0 += 32) {
    #pragma unroll
    for (int j = 0; j < 2; ++j) {
      int chunk = w * 2 + j;
      int o = chunk * 1024 + lane * 16;
      int row = o >> 6;
      int cbs = (o & 63) ^ ((row & 3) << 4);  // inverse-swizzled source (XOR involution)
      g2l16((const char*)A + ((size_t)(bm + row) * K + k0) * 2 + cbs, (char*)sA + chunk * 1024);
      g2l16((const char*)Bt + ((size_t)(bn + row) * K + k0) * 2 + cbs, (char*)sB + chunk * 1024);
    }
    __syncthreads();
    bf16x8 af[4], bfr[4];
    #pragma unroll
    for (int mf = 0; mf < 4; ++mf) {
      int row = wr * 64 + mf * 16 + li;
      int cb = (g * 16) ^ ((row & 3) << 4);
      af[mf] = ld8((const char*)sA + row * 64 + cb);
    }
    #pragma unroll
    for (int nf = 0; nf < 4; ++nf) {
      int row = wc * 64 + nf * 16 + li;
      int cb = (g * 16) ^ ((row & 3) << 4);
      bfr[nf] = ld8((const char*)sB + row * 64 + cb);
    }
    #pragma unroll
    for (int mf = 0; mf < 4; ++mf)
      #pragma unroll
      for (int nf = 0; nf < 4; ++nf)
        acc[mf][nf] = __builtin_amdgcn_mfma_f32_16x16x32_bf16(af[mf], bfr[nf], acc[mf][nf], 0, 0, 0);
    __syncthreads();
  }

  #pragma unroll
  for (int mf = 0; mf < 4; ++mf) {
    #pragma unroll
    for (int nf = 0; nf < 4; ++nf) {
      #pragma unroll
      for (int r = 0; r < 4; ++r) {
        int gm = bm + wr * 64 + mf * 16 + g * 4 + r;
        int gn = bn + wc * 64 + nf * 16 + li;
        float v = acc[mf][nf][r];
        if (mode == 0) {
          Cf[(size_t)gm * N + gn] = v;
        } else {
          // N=6144: part = gn>>11 (q/k/v), head h = (gn>>8)&7, d = gn&255
          int b = gm >> 11, s_ = gm & 2047;
          int part = gn >> 11;
          int h = (gn >> 8) & 7, d = gn & 255;
          u16* dst = part == 0 ? Qb : (part == 1 ? Kb : Vb);
          dst[((size_t)((b << 3) + h) * 2048 + s_) * 256 + d] = f2bf(v);
        }
      }
    }
  }
}

// ---------------- flash attention + fused PMSNorm ----------------
// Block: 256 thr (4 waves), q-tile 64 rows (16/wave), kv-tile 32.
// Q hoisted to regs; K-tile [32][256] (512B rows, swz (row&7)<<4); Vt-tile [256][32]
// (64B rows, swz (row&3)<<4); per-wave P [16][32] swizzled LDS for the S->A-operand transpose.
__global__ __launch_bounds__(256) void attn_kernel(
    const u16* __restrict__ Qb, const u16* __restrict__ Kb, const u16* __restrict__ Vt,
    const float* __restrict__ nw, u16* __restrict__ Mrg) {
  __shared__ __align__(16) u16 sK[32 * 256];     // 16 KiB
  __shared__ __align__(16) u16 sV[256 * 32];     // 16 KiB
  __shared__ __align__(16) u16 sP[4 * 16 * 32];  //  4 KiB

  // balance causal work: pair q-tiles i and 31-i onto CU-adjacent blocks
  int flat = blockIdx.x;
  int u = flat & 255, pp = flat >> 8;
  int bh = u & 15, i0 = u >> 4;
  int qt = pp ? 31 - i0 : i0;

  const int tid = threadIdx.x, lane = tid & 63, w = tid >> 6;
  const int g = lane >> 4, li = lane & 15;
  const float NEG = -__builtin_inff();

  // hoist Q fragments (16 rows per wave, k-contiguous 8 per lane)
  int qrow = qt * 64 + w * 16 + li;
  const u16* qp = Qb + ((size_t)bh * 2048 + qrow) * 256;
  bf16x8 qf[8];
  #pragma unroll
  for (int c = 0; c < 8; ++c) qf[c] = ld8(qp + c * 32 + g * 8);

  const f32x4 fz = {0.f, 0.f, 0.f, 0.f};
  f32x4 o[16];
  #pragma unroll
  for (int nf = 0; nf < 16; ++nf) o[nf] = fz;
  float m_[4] = {NEG, NEG, NEG, NEG};
  float l_[4] = {0.f, 0.f, 0.f, 0.f};

  const int ktn = 2 * qt + 1;  // k-tiles 0..ktn (32 wide), covers cols <= 64*qt+63
  for (int kt = 0; kt <= ktn; ++kt) {
    // stage K-tile (16KB) + Vt-tile (16KB), pre-swizzled global source
    #pragma unroll
    for (int it = 0; it < 4; ++it) {
      int o_ = it * 4096 + w * 1024 + lane * 16;
      {
        int row = o_ >> 9;
        int cbs = (o_ & 511) ^ ((row & 7) << 4);
        g2l16((const char*)Kb + ((size_t)(bh * 2048 + kt * 32 + row) * 256) * 2 + cbs,
              (char*)sK + it * 4096 + w * 1024);
      }
      {
        int row = o_ >> 6;
        int cbs = (o_ & 63) ^ ((row & 3) << 4);
        g2l16((const char*)Vt + ((size_t)(bh * 256 + row) * 2048 + kt * 32) * 2 + cbs,
              (char*)sV + it * 4096 + w * 1024);
      }
    }
    __syncthreads();

    // S = Q * K^T  (2 col-fragments of 16)
    f32x4 sacc[2] = {fz, fz};
    #pragma unroll
    for (int nf = 0; nf < 2; ++nf) {
      int row = nf * 16 + li;
      int swz = (row & 7) << 4;
      #pragma unroll
      for (int c = 0; c < 8; ++c) {
        bf16x8 kf = ld8((const char*)sK + row * 512 + ((c * 64 + g * 16) ^ swz));
        sacc[nf] = __builtin_amdgcn_mfma_f32_16x16x32_bf16(qf[c], kf, sacc[nf], 0, 0, 0);
      }
    }

    // online softmax (rows live on (g,r); cols on li) -- 16-lane xor-shuffle reductions
    float p[2][4];
    const float inv_scale = 1.0f / 64.0f;  // sqrt(256) * (LAYER_IDX+1)
    #pragma unroll
    for (int r = 0; r < 4; ++r) {
      int qr = qt * 64 + w * 16 + g * 4 + r;
      float mx = NEG;
      #pragma unroll
      for (int nf = 0; nf < 2; ++nf) {
        float x = sacc[nf][r] * inv_scale;
        int col = kt * 32 + nf * 16 + li;
        if (col > qr) x = NEG;  // causal
        p[nf][r] = x;
        mx = fmaxf(mx, x);
      }
      mx = fmaxf(mx, __shfl_xor(mx, 1));
      mx = fmaxf(mx, __shfl_xor(mx, 2));
      mx = fmaxf(mx, __shfl_xor(mx, 4));
      mx = fmaxf(mx, __shfl_xor(mx, 8));
      float mn = fmaxf(m_[r], mx);
      float sc = __expf(m_[r] - mn);
      float rs = 0.f;
      #pragma unroll
      for (int nf = 0; nf < 2; ++nf) {
        float e = __expf(p[nf][r] - mn);
        p[nf][r] = e;
        rs += e;
      }
      rs += __shfl_xor(rs, 1);
      rs += __shfl_xor(rs, 2);
      rs += __shfl_xor(rs, 4);
      rs += __shfl_xor(rs, 8);
      l_[r] = l_[r] * sc + rs;
      m_[r] = mn;
      #pragma unroll
      for (int nf = 0; nf < 16; ++nf) o[nf][r] *= sc;
    }

    // P (S-frag layout) -> per-wave swizzled LDS -> A-operand layout
    #pragma unroll
    for (int r = 0; r < 4; ++r) {
      int row = g * 4 + r;
      int swz = (row & 3) << 4;
      #pragma unroll
      for (int nf = 0; nf < 2; ++nf) {
        int ab = w * 1024 + row * 64 + ((nf * 16 + li) * 2 ^ swz);
        *(u16*)((char*)sP + ab) = f2bf(p[nf][r]);
      }
    }
    asm volatile("s_waitcnt lgkmcnt(0)" ::: "memory");  // wave-local P write->read fence

    // O += P * V   (Vt rows are d, k-contiguous in s_k)
    {
      bf16x8 pa = ld8((const char*)sP + w * 1024 + li * 64 + ((g * 16) ^ ((li & 3) << 4)));
      #pragma unroll
      for (int nf = 0; nf < 16; ++nf) {
        int row = nf * 16 + li;
        bf16x8 vf = ld8((const char*)sV + row * 64 + ((g * 16) ^ ((row & 3) << 4)));
        o[nf] = __builtin_amdgcn_mfma_f32_16x16x32_bf16(pa, vf, o[nf], 0, 0, 0);
      }
    }
    __syncthreads();
  }

  // epilogue: 1/l, PMSNorm over d (256), *norm_weight, write merged [b][s][h*256+d]
  int b = bh >> 3, h = bh & 7;
  #pragma unroll
  for (int r = 0; r < 4; ++r) {
    float inv_l = 1.0f / l_[r];
    float ss = 0.f;
    #pragma unroll
    for (int nf = 0; nf < 16; ++nf) {
      float v = o[nf][r] * inv_l;
      ss += v * v;
    }
    ss += __shfl_xor(ss, 1);
    ss += __shfl_xor(ss, 2);
    ss += __shfl_xor(ss, 4);
    ss += __shfl_xor(ss, 8);
    float rms = rsqrtf(ss * (1.0f / 256.0f) + 1e-5f);
    int row = qt * 64 + w * 16 + g * 4 + r;
    #pragma unroll
    for (int nf = 0; nf < 16; ++nf) {
      int d = nf * 16 + li;
      float v = o[nf][r] * inv_l * rms * nw[d];
      Mrg[((size_t)(b * 2048 + row)) * 2048 + h * 256 + d] = f2bf(v);
    }
  }
}

extern "C" void kernel_launch(void* const* d_in, const int* in_sizes, int n_in,
                              void* d_out, int out_size, void* d_ws, size_t ws_size,
                              hipStream_t stream) {
  const float* hs  = (const float*)d_in[0];   // [2,2048,2048]
  const float* wat = (const float*)d_in[1];   // [2048,6144]
  const float* wpr = (const float*)d_in[2];   // [2048,2048]
  const float* nw  = (const float*)d_in[3];   // [256]
  float* out = (float*)d_out;                 // [2,2048,2048] f32

  // workspace layout (88 MiB used); Wa_t scratch lives inside d_out (fully
  // overwritten by the final GEMM), Mrg aliases Xb (dead after GEMM1).
  char* ws = (char*)d_ws;
  u16* Xb   = (u16*)(ws + 0);                    // 16 MiB  [4096][2048] bf16
  u16* Wp_t = (u16*)(ws + (16u << 20));          //  8 MiB  [2048][2048] bf16 (w_proj^T)
  u16* Qb   = (u16*)(ws + (24u << 20));          // 16 MiB  [16][2048][256]
  u16* Kb2  = (u16*)(ws + (40u << 20));          // 16 MiB  [16][2048][256]
  u16* Vb   = (u16*)(ws + (56u << 20));          // 16 MiB  [16][2048][256]
  u16* Vt   = (u16*)(ws + (72u << 20));          // 16 MiB  [16][256][2048]
  u16* Mrg  = Xb;                                // [4096][2048] bf16
  u16* Wa_t = (u16*)d_out;                       // 24 MiB scratch (w_attn^T [6144][2048])

  dim3 t328(32, 8);
  cast_bf16_kernel<<<4096, 256, 0, stream>>>(hs, Xb, 1048576);
  tcast_kernel<<<dim3(192, 64), t328, 0, stream>>>(wat, Wa_t, 2048, 6144);
  tcast_kernel<<<dim3(64, 64), t328, 0, stream>>>(wpr, Wp_t, 2048, 2048);
  gemm_bt_kernel<<<dim3(48, 32), 256, 0, stream>>>(Xb, Wa_t, nullptr, Qb, Kb2, Vb,
                                                   4096, 6144, 2048, 1);
  tv_kernel<<<dim3(8, 64, 16), t328, 0, stream>>>(Vb, Vt);
  attn_kernel<<<512, 256, 0, stream>>>(Qb, Kb2, Vt, nw, Mrg);
  gemm_bt_kernel<<<dim3(16, 32), 256, 0, stream>>>(Mrg, Wp_t, out, nullptr, nullptr, nullptr,
                                                   4096, 2048, 2048, 0);
  (void)in_sizes; (void)n_in; (void)out_size; (void)ws_size;
}